// Round 1
// baseline (382.115 us; speedup 1.0000x reference)
//
#include <hip/hip_runtime.h>

// FAVOR+ causal linear attention (Performer), fp32.
// B=2, L=4096, H=8, D=64, M=128.
// 3-phase chunked scan:
//   p1: per-chunk totals of kv=sum(kf outer v), ksum=sum(kf)   (features on the fly)
//   p2: exclusive prefix over chunks per (b,h), in place
//   p3: sequential scan within chunk starting from prefix, writes out

#define B_ 2
#define L_ 4096
#define H_ 8
#define D_ 64
#define M_ 128
#define BH_ (B_*H_)          // 16
#define HD_ (H_*D_)          // 512
#define LHD_ (L_*HD_)        // 2097152
#define EC_ (M_*D_ + M_)     // 8320 state elements per chunk record
#define RATIO 0.08838834764831845f  // 1/sqrt(128)
#define EPS 1e-3f
#define PSTRIDE 65           // pad 64->65: bank (d*65+dd)%32=(d+dd)%32 -> 2-way (free)

// ---------------- Phase 1: per-chunk kv / ksum totals ----------------
__global__ __launch_bounds__(256) void p1_chunksums(
    const float* __restrict__ kk, const float* __restrict__ vv,
    const float* __restrict__ P, float* __restrict__ cs,
    int C, int CHUNK)
{
  __shared__ float P_lds[M_*PSTRIDE];
  __shared__ float kq_lds[4][64];
  __shared__ float kf_lds[4][M_];

  const int tid = threadIdx.x;
  for (int i = tid; i < M_*D_; i += 256) {
    int m = i >> 6, dd = i & 63;
    P_lds[m*PSTRIDE + dd] = P[i];
  }
  __syncthreads();

  const int w = tid >> 6, d = tid & 63;
  const int cid = blockIdx.x*4 + w;          // 4 chunks per block, one per wave
  const int bh = cid / C, c = cid % C;
  const int b = bh >> 3, h = bh & 7;

  float kv[M_];
  #pragma unroll
  for (int m = 0; m < M_; ++m) kv[m] = 0.f;
  float ks0 = 0.f, ks1 = 0.f;

  const float* Prow0 = &P_lds[d*PSTRIDE];
  const float* Prow1 = &P_lds[(d+64)*PSTRIDE];

  for (int tt = 0; tt < CHUNK; ++tt) {
    const int t = c*CHUNK + tt;
    const int gidx = b*LHD_ + t*HD_ + h*D_ + d;
    kq_lds[w][d] = kk[gidx];
    const float vd = vv[gidx];
    __syncthreads();
    float a0 = 0.f, a1 = 0.f;
    #pragma unroll
    for (int dd = 0; dd < 64; ++dd) {
      float kqv = kq_lds[w][dd];           // broadcast
      a0 = fmaf(kqv, Prow0[dd], a0);
      a1 = fmaf(kqv, Prow1[dd], a1);
    }
    float f0 = fmaxf(a0*RATIO, 0.f) + EPS;
    float f1 = fmaxf(a1*RATIO, 0.f) + EPS;
    kf_lds[w][d]    = f0;
    kf_lds[w][d+64] = f1;
    ks0 += f0; ks1 += f1;
    __syncthreads();
    #pragma unroll
    for (int m = 0; m < M_; ++m)
      kv[m] = fmaf(kf_lds[w][m], vd, kv[m]);   // broadcast reads
  }

  float* outp = &cs[(bh*C + c)*EC_];
  #pragma unroll
  for (int m = 0; m < M_; ++m) outp[m*64 + d] = kv[m];
  outp[M_*D_ + d]      = ks0;
  outp[M_*D_ + 64 + d] = ks1;
}

// ---------------- Phase 2: exclusive prefix over chunks, in place ----------------
__global__ __launch_bounds__(256) void p2_prefix(float* __restrict__ cs, int C)
{
  const int gid = blockIdx.x*256 + threadIdx.x;
  const int bh = gid / EC_, e = gid % EC_;
  if (bh >= BH_) return;
  float run = 0.f;
  int idx = bh*C*EC_ + e;
  for (int c = 0; c < C; ++c, idx += EC_) {
    float tmp = cs[idx];
    cs[idx] = run;
    run += tmp;
  }
}

// ---------------- Phase 3: within-chunk scan + output ----------------
__global__ __launch_bounds__(256) void p3_scan(
    const float* __restrict__ qq, const float* __restrict__ kk,
    const float* __restrict__ vv, const float* __restrict__ P,
    const float* __restrict__ cs, float* __restrict__ out,
    int C, int CHUNK)
{
  __shared__ float P_lds[M_*PSTRIDE];
  __shared__ float qk_lds[4][128];                    // q in [0..63], k in [64..127]
  __shared__ alignas(16) float qf_lds[4][M_];
  __shared__ alignas(16) float kf_lds[4][M_];
  __shared__ alignas(16) float ks_lds[4][M_];

  const int tid = threadIdx.x;
  for (int i = tid; i < M_*D_; i += 256) {
    int m = i >> 6, dd = i & 63;
    P_lds[m*PSTRIDE + dd] = P[i];
  }

  const int w = tid >> 6, d = tid & 63;
  const int cid = blockIdx.x*4 + w;
  const int bh = cid / C, c = cid % C;
  const int b = bh >> 3, h = bh & 7;

  const float* base = &cs[(bh*C + c)*EC_];
  float kv[M_];
  #pragma unroll
  for (int m = 0; m < M_; ++m) kv[m] = base[m*64 + d];   // coalesced
  ks_lds[w][d]    = base[M_*D_ + d];
  ks_lds[w][d+64] = base[M_*D_ + 64 + d];
  __syncthreads();

  const float* Prow0 = &P_lds[d*PSTRIDE];
  const float* Prow1 = &P_lds[(d+64)*PSTRIDE];

  for (int tt = 0; tt < CHUNK; ++tt) {
    const int t = c*CHUNK + tt;
    const int gidx = b*LHD_ + t*HD_ + h*D_ + d;
    qk_lds[w][d]    = qq[gidx];
    qk_lds[w][64+d] = kk[gidx];
    const float vd = vv[gidx];
    __syncthreads();

    float qa0=0.f, qa1=0.f, ka0=0.f, ka1=0.f;
    #pragma unroll
    for (int dd = 0; dd < 64; ++dd) {
      float qv  = qk_lds[w][dd];
      float kvv = qk_lds[w][64+dd];
      float p0  = Prow0[dd];
      float p1  = Prow1[dd];
      qa0 = fmaf(qv,  p0, qa0);
      qa1 = fmaf(qv,  p1, qa1);
      ka0 = fmaf(kvv, p0, ka0);
      ka1 = fmaf(kvv, p1, ka1);
    }
    float qf0 = fmaxf(qa0*RATIO, 0.f) + EPS;
    float qf1 = fmaxf(qa1*RATIO, 0.f) + EPS;
    float kf0 = fmaxf(ka0*RATIO, 0.f) + EPS;
    float kf1 = fmaxf(ka1*RATIO, 0.f) + EPS;
    qf_lds[w][d]    = qf0;  qf_lds[w][d+64] = qf1;
    kf_lds[w][d]    = kf0;  kf_lds[w][d+64] = kf1;
    ks_lds[w][d]    += kf0;                 // k_sum += k_t BEFORE den (matches ref)
    ks_lds[w][d+64] += kf1;
    __syncthreads();

    float num = 0.f, den = 0.f;
    const float4* qf4 = (const float4*)qf_lds[w];
    const float4* kf4 = (const float4*)kf_lds[w];
    const float4* ks4 = (const float4*)ks_lds[w];
    #pragma unroll
    for (int j = 0; j < 32; ++j) {
      float4 qv = qf4[j];
      float4 kf = kf4[j];
      float4 sv = ks4[j];
      kv[4*j+0] = fmaf(kf.x, vd, kv[4*j+0]); num = fmaf(qv.x, kv[4*j+0], num); den = fmaf(qv.x, sv.x, den);
      kv[4*j+1] = fmaf(kf.y, vd, kv[4*j+1]); num = fmaf(qv.y, kv[4*j+1], num); den = fmaf(qv.y, sv.y, den);
      kv[4*j+2] = fmaf(kf.z, vd, kv[4*j+2]); num = fmaf(qv.z, kv[4*j+2], num); den = fmaf(qv.z, sv.z, den);
      kv[4*j+3] = fmaf(kf.w, vd, kv[4*j+3]); num = fmaf(qv.w, kv[4*j+3], num); den = fmaf(qv.w, sv.w, den);
    }
    out[gidx] = num / den;
  }
}

extern "C" void kernel_launch(void* const* d_in, const int* in_sizes, int n_in,
                              void* d_out, int out_size, void* d_ws, size_t ws_size,
                              hipStream_t stream) {
  const float* q = (const float*)d_in[0];
  const float* k = (const float*)d_in[1];
  const float* v = (const float*)d_in[2];
  const float* P = (const float*)d_in[3];
  float* out = (float*)d_out;
  float* cs  = (float*)d_ws;

  // Pick largest chunk count that fits the workspace (C=128 -> 68.2 MB).
  int C = 8;
  if      (ws_size >= (size_t)BH_ * 128 * EC_ * sizeof(float)) C = 128;
  else if (ws_size >= (size_t)BH_ *  64 * EC_ * sizeof(float)) C = 64;
  else if (ws_size >= (size_t)BH_ *  32 * EC_ * sizeof(float)) C = 32;
  else if (ws_size >= (size_t)BH_ *  16 * EC_ * sizeof(float)) C = 16;
  const int CHUNK = L_ / C;

  dim3 blk(256);
  p1_chunksums<<<dim3(BH_*C/4), blk, 0, stream>>>(k, v, P, cs, C, CHUNK);
  p2_prefix  <<<dim3((BH_*EC_ + 255)/256), blk, 0, stream>>>(cs, C);
  p3_scan    <<<dim3(BH_*C/4), blk, 0, stream>>>(q, k, v, P, cs, out, C, CHUNK);
}

// Round 2
// 154.879 us; speedup vs baseline: 2.4672x; 2.4672x over previous
//
#include <hip/hip_runtime.h>

// FAVOR+ causal linear attention, fp32 I/O, bf16 MFMA chunked-GEMM form.
// B=2, L=4096, H=8, D=64, M=128.
//   p1: per chunk (T=64): Kf = relu(ratio*K P^T)+eps; KVc = Kf^T V; ksc = sum_t Kf
//   p2: exclusive prefix over chunks per (b,h)
//   p3: per chunk: Qf,Kf; S = mask(Qf Kf^T); num = Qf*KVpre + S*V;
//       den = Qf*kspre + rowsum(S); out = num/den

#define B_ 2
#define L_ 4096
#define H_ 8
#define D_ 64
#define M_ 128
#define BH_ 16
#define HD_ 512
#define LHD_ (L_*HD_)
#define EC_ (M_*D_ + M_)     // 8320 floats per chunk record
#define C_ 64                // chunks
#define T_ 64                // chunk length
#define RATIO 0.08838834764831845f
#define EPS 1e-3f

// LDS strides in shorts (all multiples of 8 for b128 alignment; %32 words == 4)
#define VT_S  72
#define KVT_S 136
#define QF_S  136
#define KF_S  136
#define SM_S  72
#define KFT_S 72

typedef __attribute__((ext_vector_type(8))) short bf16x8;
typedef __attribute__((ext_vector_type(4))) float f32x4;

__device__ __forceinline__ short f2bf(float f) {
  union { float f; unsigned u; } x; x.f = f;
  unsigned r = (x.u + 0x7fffu + ((x.u >> 16) & 1u)) >> 16;
  return (short)r;
}
__device__ __forceinline__ float bf2f(short s) {
  union { unsigned u; float f; } x; x.u = ((unsigned)(unsigned short)s) << 16;
  return x.f;
}
__device__ __forceinline__ bf16x8 load_cvt8(const float* p) {
  float4 a = *(const float4*)p;
  float4 b = *(const float4*)(p + 4);
  union { bf16x8 v; short s[8]; } u;
  u.s[0]=f2bf(a.x); u.s[1]=f2bf(a.y); u.s[2]=f2bf(a.z); u.s[3]=f2bf(a.w);
  u.s[4]=f2bf(b.x); u.s[5]=f2bf(b.y); u.s[6]=f2bf(b.z); u.s[7]=f2bf(b.w);
  return u.v;
}
#define MFMA(a,b,c) __builtin_amdgcn_mfma_f32_16x16x32_bf16((a),(b),(c),0,0,0)

// ---------------- Phase 1 ----------------
__global__ __launch_bounds__(256) void p1_mfma(
    const float* __restrict__ kk, const float* __restrict__ vv,
    const float* __restrict__ P, float* __restrict__ cs)
{
  __shared__ short Vt[64*VT_S];      // [d][t] bf16
  __shared__ short Kft[128*KFT_S];   // [m][t] bf16

  const int tid = threadIdx.x;
  const int bid = blockIdx.x;
  const int bh = bid >> 6, c = bid & 63;
  const int b = bh >> 3, h = bh & 7;
  const int lane = tid & 63, w = tid >> 6, quad = lane >> 4, l15 = lane & 15;
  const size_t gbase = (size_t)b*LHD_ + (size_t)h*D_;
  float* base = cs + (size_t)(bh*C_ + c)*EC_;

  // stage Vt (transposed, bf16) — coalesced global float4 reads
  for (int fi = tid; fi < 64*16; fi += 256) {
    int t = fi >> 4, d4 = (fi & 15) * 4;
    float4 v = *(const float4*)(vv + gbase + (size_t)(c*T_ + t)*HD_ + d4);
    Vt[(d4+0)*VT_S + t] = f2bf(v.x);
    Vt[(d4+1)*VT_S + t] = f2bf(v.y);
    Vt[(d4+2)*VT_S + t] = f2bf(v.z);
    Vt[(d4+3)*VT_S + t] = f2bf(v.w);
  }

  // Kf features for row band [16w,16w+16), written transposed -> Kft[m][t]
  const float* krow = kk + gbase + (size_t)(c*T_ + 16*w + l15)*HD_;
  bf16x8 ak0 = load_cvt8(krow + quad*8);
  bf16x8 ak1 = load_cvt8(krow + 32 + quad*8);
  #pragma unroll
  for (int ct = 0; ct < 8; ++ct) {
    const float* prow = P + (ct*16 + l15)*64;
    bf16x8 bp0 = load_cvt8(prow + quad*8);
    bf16x8 bp1 = load_cvt8(prow + 32 + quad*8);
    f32x4 ka = {0.f,0.f,0.f,0.f};
    ka = MFMA(ak0, bp0, ka);
    ka = MFMA(ak1, bp1, ka);
    #pragma unroll
    for (int reg = 0; reg < 4; ++reg) {
      int t = 16*w + quad*4 + reg;
      int m = l15 + 16*ct;
      Kft[m*KFT_S + t] = f2bf(fmaxf(ka[reg]*RATIO, 0.f) + EPS);
    }
  }
  __syncthreads();

  // ksc[m] = sum_t Kf[t][m]
  if (tid < 128) {
    float s = 0.f;
    #pragma unroll 8
    for (int t = 0; t < 64; ++t) s += bf2f(Kft[tid*KFT_S + t]);
    base[M_*D_ + tid] = s;
  }

  // KV = Kft · V  (A = Kft [128x64], B = V via Vt)
  #pragma unroll
  for (int sb = 0; sb < 2; ++sb) {
    f32x4 acc[4];
    #pragma unroll
    for (int ct = 0; ct < 4; ++ct) { f32x4 z = {0.f,0.f,0.f,0.f}; acc[ct] = z; }
    #pragma unroll
    for (int ks2 = 0; ks2 < 2; ++ks2) {
      bf16x8 a = *(const bf16x8*)&Kft[(32*w + 16*sb + l15)*KFT_S + ks2*32 + quad*8];
      #pragma unroll
      for (int ct = 0; ct < 4; ++ct) {
        bf16x8 bb = *(const bf16x8*)&Vt[(ct*16 + l15)*VT_S + ks2*32 + quad*8];
        acc[ct] = MFMA(a, bb, acc[ct]);
      }
    }
    #pragma unroll
    for (int ct = 0; ct < 4; ++ct)
      #pragma unroll
      for (int reg = 0; reg < 4; ++reg) {
        int m = 32*w + 16*sb + quad*4 + reg;
        base[m*64 + l15 + 16*ct] = acc[ct][reg];
      }
  }
}

// ---------------- Phase 2: exclusive prefix over chunks ----------------
__global__ __launch_bounds__(256) void p2_prefix(float* __restrict__ cs)
{
  const int gid = blockIdx.x*256 + threadIdx.x;
  const int bh = gid / EC_, e = gid % EC_;
  if (bh >= BH_) return;
  float run = 0.f;
  size_t idx = (size_t)bh*C_*EC_ + e;
  for (int c = 0; c < C_; ++c, idx += EC_) {
    float tmp = cs[idx];
    cs[idx] = run;
    run += tmp;
  }
}

// ---------------- Phase 3 ----------------
__global__ __launch_bounds__(256, 2) void p3_mfma(
    const float* __restrict__ qq, const float* __restrict__ kk,
    const float* __restrict__ vv, const float* __restrict__ P,
    const float* __restrict__ cs, float* __restrict__ out)
{
  __shared__ short Vt[64*VT_S];       // [d][t]
  __shared__ short KVt[64*KVT_S];     // [d][m]
  __shared__ short Qf[64*QF_S];       // [t][m]
  __shared__ short Kf[64*KF_S];       // [t][m]
  __shared__ short Sm[64*SM_S];       // [i][j]
  __shared__ float ks[128];
  __shared__ float den2p[4][64];
  __shared__ float rowsum[64];

  const int tid = threadIdx.x;
  const int bid = blockIdx.x;
  const int bh = bid >> 6, c = bid & 63;
  const int b = bh >> 3, h = bh & 7;
  const int lane = tid & 63, w = tid >> 6, quad = lane >> 4, l15 = lane & 15;
  const size_t gbase = (size_t)b*LHD_ + (size_t)h*D_;
  const float* base = cs + (size_t)(bh*C_ + c)*EC_;

  // --- stage Vt, KVt (transposed bf16), ks ---
  for (int fi = tid; fi < 64*16; fi += 256) {
    int t = fi >> 4, d4 = (fi & 15) * 4;
    float4 v = *(const float4*)(vv + gbase + (size_t)(c*T_ + t)*HD_ + d4);
    Vt[(d4+0)*VT_S + t] = f2bf(v.x);
    Vt[(d4+1)*VT_S + t] = f2bf(v.y);
    Vt[(d4+2)*VT_S + t] = f2bf(v.z);
    Vt[(d4+3)*VT_S + t] = f2bf(v.w);
  }
  for (int fi = tid; fi < 128*16; fi += 256) {
    int m = fi >> 4, d4 = (fi & 15) * 4;
    float4 v = *(const float4*)(base + m*64 + d4);
    KVt[(d4+0)*KVT_S + m] = f2bf(v.x);
    KVt[(d4+1)*KVT_S + m] = f2bf(v.y);
    KVt[(d4+2)*KVT_S + m] = f2bf(v.z);
    KVt[(d4+3)*KVT_S + m] = f2bf(v.w);
  }
  if (tid < 128) ks[tid] = base[M_*D_ + tid];

  // --- features for band [16w,16w+16): Qf, Kf row-major bf16 ---
  const float* qrow = qq + gbase + (size_t)(c*T_ + 16*w + l15)*HD_;
  const float* krow = kk + gbase + (size_t)(c*T_ + 16*w + l15)*HD_;
  bf16x8 aq0 = load_cvt8(qrow + quad*8);
  bf16x8 aq1 = load_cvt8(qrow + 32 + quad*8);
  bf16x8 ak0 = load_cvt8(krow + quad*8);
  bf16x8 ak1 = load_cvt8(krow + 32 + quad*8);
  #pragma unroll
  for (int ct = 0; ct < 8; ++ct) {
    const float* prow = P + (ct*16 + l15)*64;
    bf16x8 bp0 = load_cvt8(prow + quad*8);
    bf16x8 bp1 = load_cvt8(prow + 32 + quad*8);
    f32x4 qa = {0.f,0.f,0.f,0.f}, ka = {0.f,0.f,0.f,0.f};
    qa = MFMA(aq0, bp0, qa); qa = MFMA(aq1, bp1, qa);
    ka = MFMA(ak0, bp0, ka); ka = MFMA(ak1, bp1, ka);
    #pragma unroll
    for (int reg = 0; reg < 4; ++reg) {
      int row = 16*w + quad*4 + reg;
      int col = l15 + 16*ct;
      Qf[row*QF_S + col] = f2bf(fmaxf(qa[reg]*RATIO, 0.f) + EPS);
      Kf[row*KF_S + col] = f2bf(fmaxf(ka[reg]*RATIO, 0.f) + EPS);
    }
  }
  __syncthreads();

  // --- den part 2: Qf · ks_prefix (VALU) ---
  {
    int r = tid & 63, p = tid >> 6;
    float s = 0.f;
    #pragma unroll 8
    for (int m = 32*p; m < 32*p + 32; ++m)
      s += bf2f(Qf[r*QF_S + m]) * ks[m];
    den2p[p][r] = s;
  }

  // --- S = mask(Qf · Kf^T), band rows [16w,16w+16) ---
  {
    f32x4 sacc[4];
    #pragma unroll
    for (int jt = 0; jt < 4; ++jt) { f32x4 z = {0.f,0.f,0.f,0.f}; sacc[jt] = z; }
    #pragma unroll
    for (int ks2 = 0; ks2 < 4; ++ks2) {
      bf16x8 a = *(const bf16x8*)&Qf[(16*w + l15)*QF_S + ks2*32 + quad*8];
      #pragma unroll
      for (int jt = 0; jt < 4; ++jt) {
        bf16x8 bb = *(const bf16x8*)&Kf[(jt*16 + l15)*KF_S + ks2*32 + quad*8];
        sacc[jt] = MFMA(a, bb, sacc[jt]);
      }
    }
    float rs[4] = {0.f,0.f,0.f,0.f};
    #pragma unroll
    for (int jt = 0; jt < 4; ++jt)
      #pragma unroll
      for (int reg = 0; reg < 4; ++reg) {
        int i = 16*w + quad*4 + reg;
        int j = l15 + 16*jt;
        float val = (j <= i) ? sacc[jt][reg] : 0.f;
        rs[reg] += val;
        Sm[i*SM_S + j] = f2bf(val);
      }
    #pragma unroll
    for (int reg = 0; reg < 4; ++reg) {
      float v = rs[reg];
      v += __shfl_xor(v, 1); v += __shfl_xor(v, 2);
      v += __shfl_xor(v, 4); v += __shfl_xor(v, 8);
      if (l15 == 0) rowsum[16*w + quad*4 + reg] = v;
    }
  }
  __syncthreads();

  // --- num = Qf·KV_prefix + S·V ---
  f32x4 nacc[4];
  #pragma unroll
  for (int ct = 0; ct < 4; ++ct) { f32x4 z = {0.f,0.f,0.f,0.f}; nacc[ct] = z; }
  #pragma unroll
  for (int ks2 = 0; ks2 < 4; ++ks2) {
    bf16x8 a = *(const bf16x8*)&Qf[(16*w + l15)*QF_S + ks2*32 + quad*8];
    #pragma unroll
    for (int ct = 0; ct < 4; ++ct) {
      bf16x8 bb = *(const bf16x8*)&KVt[(ct*16 + l15)*KVT_S + ks2*32 + quad*8];
      nacc[ct] = MFMA(a, bb, nacc[ct]);
    }
  }
  #pragma unroll
  for (int ks2 = 0; ks2 < 2; ++ks2) {
    bf16x8 a = *(const bf16x8*)&Sm[(16*w + l15)*SM_S + ks2*32 + quad*8];
    #pragma unroll
    for (int ct = 0; ct < 4; ++ct) {
      bf16x8 bb = *(const bf16x8*)&Vt[(ct*16 + l15)*VT_S + ks2*32 + quad*8];
      nacc[ct] = MFMA(a, bb, nacc[ct]);
    }
  }

  // --- output ---
  #pragma unroll
  for (int reg = 0; reg < 4; ++reg) {
    int i = 16*w + quad*4 + reg;
    float den = den2p[0][i] + den2p[1][i] + den2p[2][i] + den2p[3][i] + rowsum[i];
    float inv = 1.f / den;
    #pragma unroll
    for (int ct = 0; ct < 4; ++ct) {
      int dcol = l15 + 16*ct;
      out[gbase + (size_t)(c*T_ + i)*HD_ + dcol] = nacc[ct][reg] * inv;
    }
  }
}

extern "C" void kernel_launch(void* const* d_in, const int* in_sizes, int n_in,
                              void* d_out, int out_size, void* d_ws, size_t ws_size,
                              hipStream_t stream) {
  const float* q = (const float*)d_in[0];
  const float* k = (const float*)d_in[1];
  const float* v = (const float*)d_in[2];
  const float* P = (const float*)d_in[3];
  float* out = (float*)d_out;
  float* cs  = (float*)d_ws;   // needs 16*64*8320*4 = 34.1 MB (ws >= 68 MB known)

  dim3 blk(256);
  p1_mfma  <<<dim3(BH_*C_), blk, 0, stream>>>(k, v, P, cs);
  p2_prefix<<<dim3((BH_*EC_ + 255)/256), blk, 0, stream>>>(cs);
  p3_mfma  <<<dim3(BH_*C_), blk, 0, stream>>>(q, k, v, P, cs, out);
}

// Round 3
// 146.331 us; speedup vs baseline: 2.6113x; 1.0584x over previous
//
#include <hip/hip_runtime.h>

// FAVOR+ causal linear attention, fp32 I/O, bf16 MFMA chunked-GEMM form.
// B=2, L=4096, H=8, D=64, M=128, chunks C=64 x T=64.
//   p1: Qf,Kf = relu(ratio*X P^T)+eps  -> ws (bf16, [t][m] row-major, frag-native)
//       KVt_c = (V^T Kf)  [d][m] bf16 -> cs;  ks_c = colsum(Kf) -> cs
//   p2: exclusive bf16 prefix over chunks per (b,h) (fp32 accumulate)
//   p3: num = Qf*KVpre + mask(Qf Kf^T)*V ; den = Qf*kspre + rowsum ; out = num/den
//       All GEMM operands except Vt/Sm loaded direct from global in frag layout.

#define B_ 2
#define L_ 4096
#define H_ 8
#define D_ 64
#define M_ 128
#define BH_ 16
#define HD_ 512
#define LHD_ (L_*HD_)
#define C_ 64
#define T_ 64
#define RATIO 0.08838834764831845f
#define EPS 1e-3f

#define REC_CS 8320                    // shorts per cs record: 64*128 KVt + 128 ks
#define REC_F  8192                    // shorts per Qf/Kf record: 64*128
#define CS_TOT (BH_*C_*REC_CS)         // 8519680 shorts
#define QF_OFF CS_TOT
#define KF_OFF (CS_TOT + BH_*C_*REC_F) // 16908288 shorts; total ~50.6 MB

#define VT_S  72                       // LDS row stride (shorts), 16B-aligned rows
#define KFT_S 72
#define SM_S  72

typedef __attribute__((ext_vector_type(8))) short bf16x8;
typedef __attribute__((ext_vector_type(4))) short bf16x4;
typedef __attribute__((ext_vector_type(4))) float f32x4;

__device__ __forceinline__ short f2bf(float f) {
  union { float f; unsigned u; } x; x.f = f;
  unsigned r = (x.u + 0x7fffu + ((x.u >> 16) & 1u)) >> 16;
  return (short)r;
}
__device__ __forceinline__ float bf2f(short s) {
  union { unsigned u; float f; } x; x.u = ((unsigned)(unsigned short)s) << 16;
  return x.f;
}
__device__ __forceinline__ bf16x8 load_cvt8(const float* p) {
  float4 a = *(const float4*)p;
  float4 b = *(const float4*)(p + 4);
  union { bf16x8 v; short s[8]; } u;
  u.s[0]=f2bf(a.x); u.s[1]=f2bf(a.y); u.s[2]=f2bf(a.z); u.s[3]=f2bf(a.w);
  u.s[4]=f2bf(b.x); u.s[5]=f2bf(b.y); u.s[6]=f2bf(b.z); u.s[7]=f2bf(b.w);
  return u.v;
}
#define MFMA(a,b,c) __builtin_amdgcn_mfma_f32_16x16x32_bf16((a),(b),(c),0,0,0)

// ---------------- Phase 1 ----------------
__global__ __launch_bounds__(256) void p1(
    const float* __restrict__ qq, const float* __restrict__ kk,
    const float* __restrict__ vv, const float* __restrict__ P,
    unsigned short* __restrict__ ws)
{
  __shared__ short Vt[64*VT_S];     // [d][t] bf16
  __shared__ short Kft[128*KFT_S];  // [m][t] bf16

  const int tid = threadIdx.x, bid = blockIdx.x;
  const int bh = bid >> 6, c = bid & 63;
  const int b = bh >> 3, h = bh & 7;
  const int lane = tid & 63, w = tid >> 6, quad = lane >> 4, l15 = lane & 15;
  const size_t gbase = (size_t)b*LHD_ + (size_t)h*D_;
  const int t0 = c*T_;

  // stage Vt[d][t] (transpose)
  for (int fi = tid; fi < 64*16; fi += 256) {
    int t = fi >> 4, d4 = (fi & 15)*4;
    float4 v4 = *(const float4*)(vv + gbase + (size_t)(t0+t)*HD_ + d4);
    Vt[(d4+0)*VT_S + t] = f2bf(v4.x);
    Vt[(d4+1)*VT_S + t] = f2bf(v4.y);
    Vt[(d4+2)*VT_S + t] = f2bf(v4.z);
    Vt[(d4+3)*VT_S + t] = f2bf(v4.w);
  }

  // features: rows [16w,16w+16), A=global q/k frags, B=global P frags
  const float* qrow = qq + gbase + (size_t)(t0 + 16*w + l15)*HD_;
  const float* krow = kk + gbase + (size_t)(t0 + 16*w + l15)*HD_;
  bf16x8 aq0 = load_cvt8(qrow + quad*8);
  bf16x8 aq1 = load_cvt8(qrow + 32 + quad*8);
  bf16x8 ak0 = load_cvt8(krow + quad*8);
  bf16x8 ak1 = load_cvt8(krow + 32 + quad*8);
  unsigned short* qfb = ws + QF_OFF + (size_t)(bh*C_+c)*REC_F;
  unsigned short* kfb = ws + KF_OFF + (size_t)(bh*C_+c)*REC_F;
  #pragma unroll
  for (int ct = 0; ct < 8; ++ct) {
    const float* prow = P + (ct*16 + l15)*64;
    bf16x8 bp0 = load_cvt8(prow + quad*8);
    bf16x8 bp1 = load_cvt8(prow + 32 + quad*8);
    f32x4 qa = {0.f,0.f,0.f,0.f}, ka = {0.f,0.f,0.f,0.f};
    qa = MFMA(aq0,bp0,qa); qa = MFMA(aq1,bp1,qa);
    ka = MFMA(ak0,bp0,ka); ka = MFMA(ak1,bp1,ka);
    #pragma unroll
    for (int reg = 0; reg < 4; ++reg) {
      int trow = 16*w + quad*4 + reg;
      int m = l15 + 16*ct;
      short qv = f2bf(fmaxf(qa[reg]*RATIO, 0.f) + EPS);
      short kv = f2bf(fmaxf(ka[reg]*RATIO, 0.f) + EPS);
      qfb[trow*128 + m] = (unsigned short)qv;
      kfb[trow*128 + m] = (unsigned short)kv;
      Kft[m*KFT_S + trow] = kv;
    }
  }
  __syncthreads();

  // KV^T[d][m] = sum_t Vt[d][t]*Kf[t][m];  wave w owns d in [16w,16w+16)
  unsigned short* csb = ws + (size_t)(bh*C_+c)*REC_CS;
  bf16x8 av0 = *(const bf16x8*)&Vt[(16*w + l15)*VT_S + quad*8];
  bf16x8 av1 = *(const bf16x8*)&Vt[(16*w + l15)*VT_S + 32 + quad*8];
  #pragma unroll
  for (int mt = 0; mt < 8; ++mt) {
    f32x4 acc = {0.f,0.f,0.f,0.f};
    bf16x8 b0 = *(const bf16x8*)&Kft[(16*mt + l15)*KFT_S + quad*8];
    bf16x8 b1 = *(const bf16x8*)&Kft[(16*mt + l15)*KFT_S + 32 + quad*8];
    acc = MFMA(av0, b0, acc);
    acc = MFMA(av1, b1, acc);
    #pragma unroll
    for (int reg = 0; reg < 4; ++reg) {
      int d = 16*w + quad*4 + reg;
      int m = l15 + 16*mt;
      csb[d*128 + m] = (unsigned short)f2bf(acc[reg]);
    }
  }
  // ks[m] = sum_t Kf[t][m]
  if (tid < 128) {
    float s = 0.f;
    #pragma unroll 8
    for (int t = 0; t < 64; ++t) s += bf2f(Kft[tid*KFT_S + t]);
    csb[64*128 + tid] = (unsigned short)f2bf(s);
  }
}

// ---------------- Phase 2: bf16 exclusive prefix (fp32 accum) ----------------
__global__ __launch_bounds__(256) void p2(unsigned short* __restrict__ ws)
{
  const int gid = blockIdx.x*256 + threadIdx.x;   // 4 shorts per thread
  if (gid >= BH_*(REC_CS/4)) return;
  const int bh = gid / (REC_CS/4), g = gid % (REC_CS/4);
  unsigned short* base = ws + (size_t)bh*C_*REC_CS + g*4;
  float run[4] = {0.f,0.f,0.f,0.f};
  #pragma unroll 1
  for (int c = 0; c < C_; c += 4) {
    bf16x4 r[4];
    #pragma unroll
    for (int u = 0; u < 4; ++u)
      r[u] = *(const bf16x4*)(base + (size_t)(c+u)*REC_CS);
    #pragma unroll
    for (int u = 0; u < 4; ++u) {
      union { bf16x4 v; short s[4]; } wv;
      #pragma unroll
      for (int j = 0; j < 4; ++j) { wv.s[j] = f2bf(run[j]); run[j] += bf2f(r[u][j]); }
      *(bf16x4*)(base + (size_t)(c+u)*REC_CS) = wv.v;
    }
  }
}

// ---------------- Phase 3 ----------------
__global__ __launch_bounds__(256) void p3(
    const float* __restrict__ vv, const unsigned short* __restrict__ ws,
    float* __restrict__ out)
{
  __shared__ short Vt[64*VT_S];   // [d][t]
  __shared__ short Sm[64*SM_S];   // [i][j]
  __shared__ float ks_lds[128];

  const int tid = threadIdx.x, bid = blockIdx.x;
  const int bh = bid >> 6, c = bid & 63;
  const int b = bh >> 3, h = bh & 7;
  const int lane = tid & 63, w = tid >> 6, quad = lane >> 4, l15 = lane & 15;
  const size_t gbase = (size_t)b*LHD_ + (size_t)h*D_;
  const int t0 = c*T_;
  const unsigned short* csb = ws + (size_t)(bh*C_+c)*REC_CS;
  const unsigned short* qfb = ws + QF_OFF + (size_t)(bh*C_+c)*REC_F;
  const unsigned short* kfb = ws + KF_OFF + (size_t)(bh*C_+c)*REC_F;

  // stage Vt[d][t]
  for (int fi = tid; fi < 64*16; fi += 256) {
    int t = fi >> 4, d4 = (fi & 15)*4;
    float4 v4 = *(const float4*)(vv + gbase + (size_t)(t0+t)*HD_ + d4);
    Vt[(d4+0)*VT_S + t] = f2bf(v4.x);
    Vt[(d4+1)*VT_S + t] = f2bf(v4.y);
    Vt[(d4+2)*VT_S + t] = f2bf(v4.z);
    Vt[(d4+3)*VT_S + t] = f2bf(v4.w);
  }
  if (tid < 128) ks_lds[tid] = bf2f((short)csb[64*128 + tid]);

  // Qf A-frags: row 16w+l15, k-slices — direct global loads
  bf16x8 qf[4];
  #pragma unroll
  for (int ks2 = 0; ks2 < 4; ++ks2)
    qf[ks2] = *(const bf16x8*)(qfb + (16*w + l15)*128 + ks2*32 + quad*8);

  __syncthreads();

  // num1 = Qf * KV_prefix (B-frags direct from cs, [d][m] bf16)
  f32x4 nacc[4];
  #pragma unroll
  for (int ct = 0; ct < 4; ++ct) { f32x4 z = {0.f,0.f,0.f,0.f}; nacc[ct] = z; }
  #pragma unroll
  for (int ks2 = 0; ks2 < 4; ++ks2) {
    #pragma unroll
    for (int ct = 0; ct < 4; ++ct) {
      bf16x8 bb = *(const bf16x8*)(csb + (16*ct + l15)*128 + ks2*32 + quad*8);
      nacc[ct] = MFMA(qf[ks2], bb, nacc[ct]);
    }
  }

  // den part 1: Qf . ks_prefix  (per-lane partial over its 32 cols, reduce quads)
  float dp = 0.f;
  #pragma unroll
  for (int ks2 = 0; ks2 < 4; ++ks2)
    #pragma unroll
    for (int j = 0; j < 8; ++j)
      dp += bf2f(qf[ks2][j]) * ks_lds[ks2*32 + quad*8 + j];
  dp += __shfl_xor(dp, 16);
  dp += __shfl_xor(dp, 32);   // dp on (quad,l15) = den1 for row 16w+l15

  // S = mask(Qf Kf^T)  (B-frags direct from Kf ws, [j][m] bf16)
  f32x4 sacc[4];
  #pragma unroll
  for (int jt = 0; jt < 4; ++jt) { f32x4 z = {0.f,0.f,0.f,0.f}; sacc[jt] = z; }
  #pragma unroll
  for (int ks2 = 0; ks2 < 4; ++ks2) {
    #pragma unroll
    for (int jt = 0; jt < 4; ++jt) {
      bf16x8 bb = *(const bf16x8*)(kfb + (16*jt + l15)*128 + ks2*32 + quad*8);
      sacc[jt] = MFMA(qf[ks2], bb, sacc[jt]);
    }
  }
  float rs[4] = {0.f,0.f,0.f,0.f};
  #pragma unroll
  for (int jt = 0; jt < 4; ++jt)
    #pragma unroll
    for (int reg = 0; reg < 4; ++reg) {
      int row = 16*w + quad*4 + reg;
      int j = l15 + 16*jt;
      float val = (j <= row) ? sacc[jt][reg] : 0.f;
      rs[reg] += val;
      Sm[row*SM_S + j] = f2bf(val);
    }
  #pragma unroll
  for (int reg = 0; reg < 4; ++reg) {
    rs[reg] += __shfl_xor(rs[reg], 1);
    rs[reg] += __shfl_xor(rs[reg], 2);
    rs[reg] += __shfl_xor(rs[reg], 4);
    rs[reg] += __shfl_xor(rs[reg], 8);   // all lanes of quad: rowsum(row=16w+4q+reg)
  }

  // num2 = S * V  (A=Sm own-wave rows, B=Vt; same-wave LDS ordering, no barrier)
  #pragma unroll
  for (int ks = 0; ks < 2; ++ks) {
    bf16x8 a = *(const bf16x8*)&Sm[(16*w + l15)*SM_S + ks*32 + quad*8];
    #pragma unroll
    for (int ct = 0; ct < 4; ++ct) {
      bf16x8 bb = *(const bf16x8*)&Vt[(16*ct + l15)*VT_S + ks*32 + quad*8];
      nacc[ct] = MFMA(a, bb, nacc[ct]);
    }
  }

  // out = num/den; den for row 16w+4*quad+reg = shfl(dp) + rs[reg]
  #pragma unroll
  for (int reg = 0; reg < 4; ++reg) {
    float den1 = __shfl(dp, 4*quad + reg);   // from quad-0 lane with l15=4q+reg
    float inv = 1.f / (den1 + rs[reg]);
    int trow = t0 + 16*w + quad*4 + reg;
    #pragma unroll
    for (int ct = 0; ct < 4; ++ct)
      out[gbase + (size_t)trow*HD_ + 16*ct + l15] = nacc[ct][reg] * inv;
  }
}

extern "C" void kernel_launch(void* const* d_in, const int* in_sizes, int n_in,
                              void* d_out, int out_size, void* d_ws, size_t ws_size,
                              hipStream_t stream) {
  const float* q = (const float*)d_in[0];
  const float* k = (const float*)d_in[1];
  const float* v = (const float*)d_in[2];
  const float* P = (const float*)d_in[3];
  float* out = (float*)d_out;
  unsigned short* ws = (unsigned short*)d_ws;  // needs ~50.6 MB

  dim3 blk(256);
  p1<<<dim3(BH_*C_), blk, 0, stream>>>(q, k, v, P, ws);
  p2<<<dim3((BH_*(REC_CS/4) + 255)/256), blk, 0, stream>>>(ws);
  p3<<<dim3(BH_*C_), blk, 0, stream>>>(v, ws, out);
}